// Round 11
// baseline (399.253 us; speedup 1.0000x reference)
//
#include <hip/hip_runtime.h>
#include <hip/hip_bf16.h>

// ConvexReLUCNN: B=512, C=3, H=W=64, KERNEL=3
//   K=27, L=62*62=3844, M=512, O=10
#define ODIM   10
#define HOg    62
#define LDIM   3844
#define CHW    12288
#define BATCH  512
#define KO     270
#define KOP    272        // ko padded to 17*16
#define MDIM   512        // reduction dim (neurons)
#define REP    16         // diagnostic inflation of tmfma (divide its dur by 16)

typedef __attribute__((ext_vector_type(8))) short bfrag;   // 8 bf16 (4 VGPR)
typedef __attribute__((ext_vector_type(4))) float f32x4;

// ---------------------------------------------------------------------------
// K0 prep, 1052 blocks:
//   [0,488):    Gt[n][m] (bf16) = G[m][n], 64x64 LDS-tiled transpose
//   [488,1032): Pdt[ko][m] (bf16) = v[m][ko]-w[m][ko]  (ko>=270 -> 0)
//   [1032,1052): out = 0  (out_gemm accumulates with atomics)
// ---------------------------------------------------------------------------
__global__ __launch_bounds__(256)
void prep_kernel(const float* __restrict__ G,
                 const float* __restrict__ v, const float* __restrict__ w,
                 __hip_bfloat16* __restrict__ Gt,
                 __hip_bfloat16* __restrict__ Pdt,
                 float* __restrict__ out) {
    const int b = blockIdx.x;
    if (b < 488) {
        __shared__ float tile[64][65];
        const int nTile = b % 61;
        const int mTile = b / 61;          // 0..7
        const int n0 = nTile * 64;
        const int m0 = mTile * 64;
        const int tc = threadIdx.x & 63;
        const int tr = threadIdx.x >> 6;
#pragma unroll
        for (int rr = 0; rr < 64; rr += 4) {
            int n = n0 + tc;
            tile[rr + tr][tc] = (n < LDIM) ? G[(size_t)(m0 + rr + tr) * LDIM + n] : 0.f;
        }
        __syncthreads();
        const int nr = threadIdx.x >> 2;          // n-row within tile
        const int ms = (threadIdx.x & 3) * 16;    // m-segment
        __hip_bfloat16 buf[16];
#pragma unroll
        for (int i = 0; i < 16; ++i)
            buf[i] = __float2bfloat16(tile[ms + i][nr]);
        __hip_bfloat16* dst = Gt + (size_t)(n0 + nr) * MDIM + m0 + ms;
        *reinterpret_cast<uint4*>(dst)     = *reinterpret_cast<uint4*>(&buf[0]);
        *reinterpret_cast<uint4*>(dst + 8) = *reinterpret_cast<uint4*>(&buf[8]);
    } else if (b < 1032) {
        int idx = (b - 488) * 256 + threadIdx.x;   // m*KOP + ko, exact range
        int m  = idx / KOP;
        int ko = idx - m * KOP;
        float val = (ko < KO) ? (v[m * KO + ko] - w[m * KO + ko]) : 0.f;
        Pdt[(size_t)ko * MDIM + m] = __float2bfloat16(val);
    } else {
        int idx = (b - 1032) * 256 + threadIdx.x;  // 20*256 = 5120 exact
        out[idx] = 0.f;
    }
}

// ---------------------------------------------------------------------------
// K1: T[ko][n] = sum_m Pdt[ko][m]*Gt[n][m]  (mfma 16x16x32 bf16, verified
// round 8/9). DIAGNOSTIC: body repeated REP times (idempotent T writes,
// memory-clobber per rep so loads/stores re-execute) to surface this
// kernel's true per-rep cost above the harness's ~40us fill dispatches.
// ---------------------------------------------------------------------------
__global__ __launch_bounds__(256)
void tmfma_kernel(const __hip_bfloat16* __restrict__ Pdt,
                  const __hip_bfloat16* __restrict__ Gt,
                  float* __restrict__ T) {
    const int bid   = blockIdx.x;
    const int xcd   = bid & 7;
    const int inner = bid >> 3;        // 0..33
    const int sthi  = inner & 1;
    const int kt    = inner >> 1;      // ko-tile 0..16
    const int st    = xcd + 8 * sthi;  // n-supertile 0..15

    const int wv   = threadIdx.x >> 6;
    const int lane = threadIdx.x & 63;
    const int tile = st * 4 + wv;      // n-tile of 64
    if (tile >= 61) return;

    const int n0  = tile * 64;
    const int ko0 = kt * 16;
    const int row = lane & 15;
    const int kg  = lane >> 4;         // 0..3

    const __hip_bfloat16* Ap = Pdt + (size_t)(ko0 + row) * MDIM + kg * 8;
    const __hip_bfloat16* Bp = Gt  + (size_t)(n0 + row) * MDIM + kg * 8;

#pragma unroll 1
    for (int rep = 0; rep < REP; ++rep) {
        asm volatile("" ::: "memory");   // force re-execution each rep

        bfrag a[16];
#pragma unroll
        for (int ks = 0; ks < 16; ++ks)
            a[ks] = *reinterpret_cast<const bfrag*>(Ap + ks * 32);

        f32x4 acc[4];
#pragma unroll
        for (int j = 0; j < 4; ++j) acc[j] = (f32x4){0.f, 0.f, 0.f, 0.f};

#pragma unroll 4
        for (int ks = 0; ks < 16; ++ks) {
#pragma unroll
            for (int j = 0; j < 4; ++j) {
                bfrag bfr = *reinterpret_cast<const bfrag*>(
                    Bp + (size_t)j * 16 * MDIM + ks * 32);
                acc[j] = __builtin_amdgcn_mfma_f32_16x16x32_bf16(a[ks], bfr, acc[j], 0, 0, 0);
            }
        }

#pragma unroll
        for (int j = 0; j < 4; ++j) {
            int col = n0 + j * 16 + row;
            if (col < LDIM) {
#pragma unroll
                for (int r = 0; r < 4; ++r) {
                    int ro = ko0 + kg * 4 + r;
                    if (ro < KO)
                        T[(size_t)ro * LDIM + col] = acc[j][r];
                }
            }
        }
    }
}

// ---------------------------------------------------------------------------
// K2: fold T (ko, pix) -> S[o][c*4096 + h*64 + w] (full overwrite, no zeroing)
// ---------------------------------------------------------------------------
__global__ __launch_bounds__(256)
void fold_kernel(const float* __restrict__ T, float* __restrict__ S) {
    int idx = blockIdx.x * 256 + threadIdx.x;   // o*CHW + chw
    if (idx >= ODIM * CHW) return;
    int o   = idx / CHW;
    int chw = idx - o * CHW;
    int c = chw >> 12;
    int h = (chw >> 6) & 63;
    int w = chw & 63;

    float s = 0.f;
    for (int i = 0; i < 3; ++i) {
        int pi = h - i;
        if ((unsigned)pi >= HOg) continue;
        for (int j = 0; j < 3; ++j) {
            int pj = w - j;
            if ((unsigned)pj >= HOg) continue;
            int ko = (c * 9 + i * 3 + j) * ODIM + o;
            s += T[(size_t)ko * LDIM + pi * HOg + pj];
        }
    }
    S[idx] = s;
}

// ---------------------------------------------------------------------------
// K3: out[b][o] += sum_{chw in slice} x[b][chw] * S[o][chw]
// Grid 384 = 64 image-octets x 6 chw-slices (2048 floats each).
// Each S float4 is loaded ONCE per block and reused for 8 images in
// registers -> S global traffic 125 MB -> 31 MB. Partials atomicAdd'ed
// into prep-zeroed out.
// ---------------------------------------------------------------------------
__global__ __launch_bounds__(256)
void out_gemm_kernel(const float* __restrict__ X,
                     const float* __restrict__ S,
                     float* __restrict__ out) {
    const int bg = blockIdx.x / 6;     // image octet
    const int sl = blockIdx.x % 6;     // chw slice
    const int b0 = bg * 8;
    const int i0 = sl * 512;           // float4 index base of slice
    const int tid = threadIdx.x;
    const int NV = CHW / 4;            // 3072

    const float4* X4 = reinterpret_cast<const float4*>(X);
    const float4* S4 = reinterpret_cast<const float4*>(S);

    float acc[8][ODIM];
#pragma unroll
    for (int im = 0; im < 8; ++im)
#pragma unroll
        for (int o = 0; o < ODIM; ++o) acc[im][o] = 0.f;

#pragma unroll
    for (int ii = 0; ii < 2; ++ii) {
        int i = i0 + tid + ii * 256;
        float4 xv[8];
#pragma unroll
        for (int im = 0; im < 8; ++im)
            xv[im] = X4[(size_t)(b0 + im) * NV + i];
#pragma unroll
        for (int o = 0; o < ODIM; ++o) {
            float4 sv = S4[(size_t)o * NV + i];
#pragma unroll
            for (int im = 0; im < 8; ++im) {
                acc[im][o] += xv[im].x * sv.x + xv[im].y * sv.y
                            + xv[im].z * sv.z + xv[im].w * sv.w;
            }
        }
    }

    // wave butterfly reduce all 80 accumulators
#pragma unroll
    for (int im = 0; im < 8; ++im)
#pragma unroll
        for (int o = 0; o < ODIM; ++o) {
            float s = acc[im][o];
            for (int off = 32; off > 0; off >>= 1)
                s += __shfl_down(s, off, 64);
            acc[im][o] = s;
        }

    __shared__ float red[4][80];
    const int wave = tid >> 6;
    const int lane = tid & 63;
    if (lane == 0) {
#pragma unroll
        for (int im = 0; im < 8; ++im)
#pragma unroll
            for (int o = 0; o < ODIM; ++o)
                red[wave][im * ODIM + o] = acc[im][o];
    }
    __syncthreads();
    if (tid < 80) {
        float t = red[0][tid] + red[1][tid] + red[2][tid] + red[3][tid];
        int im = tid / ODIM;
        int o  = tid - im * ODIM;
        atomicAdd(&out[(size_t)(b0 + im) * ODIM + o], t);
    }
}

extern "C" void kernel_launch(void* const* d_in, const int* in_sizes, int n_in,
                              void* d_out, int out_size, void* d_ws, size_t ws_size,
                              hipStream_t stream) {
    const float* x = (const float*)d_in[0];   // (512, 3, 64, 64)
    const float* G = (const float*)d_in[1];   // (512, 3844)
    const float* v = (const float*)d_in[2];   // (512, 27, 10)
    const float* w = (const float*)d_in[3];   // (512, 27, 10)
    float* out = (float*)d_out;               // (512, 10)

    // ws layout:
    //   T   fp32 [270][3844] = 4,151,520 B
    //   Gt  bf16 [3904][512] = 3,997,696 B
    //   Pdt bf16 [272][512]  =   278,528 B
    //   S   fp32 [10][12288] =   491,520 B
    char* wsb = (char*)d_ws;
    float*          T   = (float*)wsb;
    __hip_bfloat16* Gt  = (__hip_bfloat16*)(wsb + 4151520);
    __hip_bfloat16* Pdt = (__hip_bfloat16*)(wsb + 4151520 + 3997696);
    float*          S   = (float*)(wsb + 4151520 + 3997696 + 278528);

    prep_kernel<<<1052, 256, 0, stream>>>(G, v, w, Gt, Pdt, out);

    tmfma_kernel<<<272, 256, 0, stream>>>(Pdt, Gt, T);

    fold_kernel<<<(ODIM * CHW + 255) / 256, 256, 0, stream>>>(T, S);

    out_gemm_kernel<<<384, 256, 0, stream>>>(x, S, out);
}

// Round 12
// 48.089 us; speedup vs baseline: 8.3024x; 8.3024x over previous
//
#include <hip/hip_runtime.h>
#include <hip/hip_bf16.h>

// ConvexReLUCNN: B=512, C=3, H=W=64, KERNEL=3
//   K=27, L=62*62=3844, M=512, O=10
#define ODIM   10
#define HOg    62
#define LDIM   3844
#define CHW    12288
#define BATCH  512
#define KO     270
#define KOP    272        // ko padded to 17*16
#define MDIM   512        // reduction dim (neurons)
#define TPSTR  ((size_t)KO * LDIM)    // per-partial stride (floats)

typedef __attribute__((ext_vector_type(8))) short bfrag;   // 8 bf16 (4 VGPR)
typedef __attribute__((ext_vector_type(4))) float f32x4;

// ---------------------------------------------------------------------------
// K0 prep, 1052 blocks:
//   [0,488):    Gt[n][m] (bf16) = G[m][n], 64x64 LDS-tiled transpose
//   [488,1032): Pdt[ko][m] (bf16) = v[m][ko]-w[m][ko]  (ko>=270 -> 0)
//   [1032,1052): out = 0  (out_gemm accumulates with atomics)
// ---------------------------------------------------------------------------
__global__ __launch_bounds__(256)
void prep_kernel(const float* __restrict__ G,
                 const float* __restrict__ v, const float* __restrict__ w,
                 __hip_bfloat16* __restrict__ Gt,
                 __hip_bfloat16* __restrict__ Pdt,
                 float* __restrict__ out) {
    const int b = blockIdx.x;
    if (b < 488) {
        __shared__ float tile[64][65];
        const int nTile = b % 61;
        const int mTile = b / 61;          // 0..7
        const int n0 = nTile * 64;
        const int m0 = mTile * 64;
        const int tc = threadIdx.x & 63;
        const int tr = threadIdx.x >> 6;
#pragma unroll
        for (int rr = 0; rr < 64; rr += 4) {
            int n = n0 + tc;
            tile[rr + tr][tc] = (n < LDIM) ? G[(size_t)(m0 + rr + tr) * LDIM + n] : 0.f;
        }
        __syncthreads();
        const int nr = threadIdx.x >> 2;          // n-row within tile
        const int ms = (threadIdx.x & 3) * 16;    // m-segment
        __hip_bfloat16 buf[16];
#pragma unroll
        for (int i = 0; i < 16; ++i)
            buf[i] = __float2bfloat16(tile[ms + i][nr]);
        __hip_bfloat16* dst = Gt + (size_t)(n0 + nr) * MDIM + m0 + ms;
        *reinterpret_cast<uint4*>(dst)     = *reinterpret_cast<uint4*>(&buf[0]);
        *reinterpret_cast<uint4*>(dst + 8) = *reinterpret_cast<uint4*>(&buf[8]);
    } else if (b < 1032) {
        int idx = (b - 488) * 256 + threadIdx.x;   // m*KOP + ko, exact range
        int m  = idx / KOP;
        int ko = idx - m * KOP;
        float val = (ko < KO) ? (v[m * KO + ko] - w[m * KO + ko]) : 0.f;
        Pdt[(size_t)ko * MDIM + m] = __float2bfloat16(val);
    } else {
        int idx = (b - 1032) * 256 + threadIdx.x;  // 20*256 = 5120 exact
        out[idx] = 0.f;
    }
}

// ---------------------------------------------------------------------------
// K1: Tp[kc][ko][n] = sum_{m in K-chunk kc} Pdt[ko][m]*Gt[n][m]
// (mfma 16x16x32 bf16, fragment mapping verified rounds 8-11.)
// 1037 blocks x 4 waves; wave wv = K-chunk kc (128 m each) of the block's
// (kt, tile) output tile -> 4148 wave-units, 4 blocks/CU, 16 waves/CU
// (round-11 fix: occupancy was 1 wave/SIMD). No A-array preload and
// __launch_bounds__(256,4) (<=128 VGPR) to avoid the round-11 spill
// (VGPR=60 forced a[16] to scratch: 300 MB spill traffic).
// Bijective XCD swizzle (m204, nwg=1037=129*8+5): consecutive logical
// blocks (which share the Gt tile-panel: kt = lb%17, tile = lb/17) land
// on one XCD -> Gt HBM-fetched ~once.
// ---------------------------------------------------------------------------
__global__ __launch_bounds__(256, 4)
void tmfma_kernel(const __hip_bfloat16* __restrict__ Pdt,
                  const __hip_bfloat16* __restrict__ Gt,
                  float* __restrict__ Tp) {
    const int orig = blockIdx.x;          // 0..1036
    const int xcd  = orig & 7;
    const int base = orig >> 3;
    const int lb   = (xcd < 5 ? xcd * 130 : 650 + (xcd - 5) * 129) + base;
    const int kt   = lb % 17;             // ko-tile
    const int tile = lb / 17;             // n-tile 0..60

    const int wv   = threadIdx.x >> 6;    // K-chunk kc 0..3
    const int lane = threadIdx.x & 63;
    const int n0   = tile * 64;
    const int ko0  = kt * 16;
    const int row  = lane & 15;
    const int kg   = lane >> 4;           // 0..3

    const __hip_bfloat16* Ap = Pdt + (size_t)(ko0 + row) * MDIM + wv * 128 + kg * 8;
    const __hip_bfloat16* Bp = Gt  + (size_t)(n0 + row) * MDIM + wv * 128 + kg * 8;

    f32x4 acc[4];
#pragma unroll
    for (int j = 0; j < 4; ++j) acc[j] = (f32x4){0.f, 0.f, 0.f, 0.f};

#pragma unroll
    for (int ks = 0; ks < 4; ++ks) {
        bfrag a = *reinterpret_cast<const bfrag*>(Ap + ks * 32);
#pragma unroll
        for (int j = 0; j < 4; ++j) {
            bfrag bfr = *reinterpret_cast<const bfrag*>(
                Bp + (size_t)j * 16 * MDIM + ks * 32);
            acc[j] = __builtin_amdgcn_mfma_f32_16x16x32_bf16(a, bfr, acc[j], 0, 0, 0);
        }
    }

    float* tb = Tp + (size_t)wv * TPSTR;
#pragma unroll
    for (int j = 0; j < 4; ++j) {
        int col = n0 + j * 16 + row;
        if (col < LDIM) {
#pragma unroll
            for (int r = 0; r < 4; ++r) {
                int ro = ko0 + kg * 4 + r;
                if (ro < KO)
                    tb[(size_t)ro * LDIM + col] = acc[j][r];
            }
        }
    }
}

// ---------------------------------------------------------------------------
// K2: fold 4 fp32 partials (ko, pix) -> S[o][c*4096 + h*64 + w]
// ---------------------------------------------------------------------------
__global__ __launch_bounds__(256)
void fold_kernel(const float* __restrict__ Tp, float* __restrict__ S) {
    int idx = blockIdx.x * 256 + threadIdx.x;   // o*CHW + chw
    if (idx >= ODIM * CHW) return;
    int o   = idx / CHW;
    int chw = idx - o * CHW;
    int c = chw >> 12;
    int h = (chw >> 6) & 63;
    int w = chw & 63;

    float s = 0.f;
    for (int i = 0; i < 3; ++i) {
        int pi = h - i;
        if ((unsigned)pi >= HOg) continue;
        for (int j = 0; j < 3; ++j) {
            int pj = w - j;
            if ((unsigned)pj >= HOg) continue;
            int ko = (c * 9 + i * 3 + j) * ODIM + o;
            size_t off = (size_t)ko * LDIM + pi * HOg + pj;
#pragma unroll
            for (int p = 0; p < 4; ++p)
                s += Tp[(size_t)p * TPSTR + off];
        }
    }
    S[idx] = s;
}

// ---------------------------------------------------------------------------
// K3: out[b][o] += sum_{chw in slice} x[b][chw] * S[o][chw]
// Grid 384 = 64 image-octets x 6 chw-slices; S float4 reused for 8 images.
// ---------------------------------------------------------------------------
__global__ __launch_bounds__(256)
void out_gemm_kernel(const float* __restrict__ X,
                     const float* __restrict__ S,
                     float* __restrict__ out) {
    const int bg = blockIdx.x / 6;     // image octet
    const int sl = blockIdx.x % 6;     // chw slice
    const int b0 = bg * 8;
    const int i0 = sl * 512;           // float4 index base of slice
    const int tid = threadIdx.x;
    const int NV = CHW / 4;            // 3072

    const float4* X4 = reinterpret_cast<const float4*>(X);
    const float4* S4 = reinterpret_cast<const float4*>(S);

    float acc[8][ODIM];
#pragma unroll
    for (int im = 0; im < 8; ++im)
#pragma unroll
        for (int o = 0; o < ODIM; ++o) acc[im][o] = 0.f;

#pragma unroll
    for (int ii = 0; ii < 2; ++ii) {
        int i = i0 + tid + ii * 256;
        float4 xv[8];
#pragma unroll
        for (int im = 0; im < 8; ++im)
            xv[im] = X4[(size_t)(b0 + im) * NV + i];
#pragma unroll
        for (int o = 0; o < ODIM; ++o) {
            float4 sv = S4[(size_t)o * NV + i];
#pragma unroll
            for (int im = 0; im < 8; ++im) {
                acc[im][o] += xv[im].x * sv.x + xv[im].y * sv.y
                            + xv[im].z * sv.z + xv[im].w * sv.w;
            }
        }
    }

#pragma unroll
    for (int im = 0; im < 8; ++im)
#pragma unroll
        for (int o = 0; o < ODIM; ++o) {
            float s = acc[im][o];
            for (int off = 32; off > 0; off >>= 1)
                s += __shfl_down(s, off, 64);
            acc[im][o] = s;
        }

    __shared__ float red[4][80];
    const int wave = tid >> 6;
    const int lane = tid & 63;
    if (lane == 0) {
#pragma unroll
        for (int im = 0; im < 8; ++im)
#pragma unroll
            for (int o = 0; o < ODIM; ++o)
                red[wave][im * ODIM + o] = acc[im][o];
    }
    __syncthreads();
    if (tid < 80) {
        float t = red[0][tid] + red[1][tid] + red[2][tid] + red[3][tid];
        int im = tid / ODIM;
        int o  = tid - im * ODIM;
        atomicAdd(&out[(size_t)(b0 + im) * ODIM + o], t);
    }
}

extern "C" void kernel_launch(void* const* d_in, const int* in_sizes, int n_in,
                              void* d_out, int out_size, void* d_ws, size_t ws_size,
                              hipStream_t stream) {
    const float* x = (const float*)d_in[0];   // (512, 3, 64, 64)
    const float* G = (const float*)d_in[1];   // (512, 3844)
    const float* v = (const float*)d_in[2];   // (512, 27, 10)
    const float* w = (const float*)d_in[3];   // (512, 27, 10)
    float* out = (float*)d_out;               // (512, 10)

    // ws layout:
    //   Tp  fp32 4x[270][3844] = 16,606,080 B
    //   Gt  bf16 [3904][512]   =  3,997,696 B
    //   Pdt bf16 [272][512]    =    278,528 B
    //   S   fp32 [10][12288]   =    491,520 B
    char* wsb = (char*)d_ws;
    float*          Tp  = (float*)wsb;
    __hip_bfloat16* Gt  = (__hip_bfloat16*)(wsb + 16606080);
    __hip_bfloat16* Pdt = (__hip_bfloat16*)(wsb + 16606080 + 3997696);
    float*          S   = (float*)(wsb + 16606080 + 3997696 + 278528);

    prep_kernel<<<1052, 256, 0, stream>>>(G, v, w, Gt, Pdt, out);

    tmfma_kernel<<<1037, 256, 0, stream>>>(Pdt, Gt, Tp);

    fold_kernel<<<(ODIM * CHW + 255) / 256, 256, 0, stream>>>(Tp, S);

    out_gemm_kernel<<<384, 256, 0, stream>>>(x, S, out);
}

// Round 13
// 46.299 us; speedup vs baseline: 8.6233x; 1.0386x over previous
//
#include <hip/hip_runtime.h>
#include <hip/hip_bf16.h>

// ConvexReLUCNN: B=512, C=3, H=W=64, KERNEL=3
//   K=27, L=62*62=3844, M=512, O=10
#define ODIM   10
#define HOg    62
#define LDIM   3844
#define CHW    12288
#define BATCH  512
#define KO     270
#define KOP    272        // ko padded to 17*16
#define MDIM   512        // reduction dim (neurons)

typedef __attribute__((ext_vector_type(8))) short bfrag;   // 8 bf16 (4 VGPR)
typedef __attribute__((ext_vector_type(4))) float f32x4;

// ---------------------------------------------------------------------------
// K0 prep, 1052 blocks:
//   [0,488):    Gt[n][m] (bf16) = G[m][n], 64x64 LDS-tiled transpose
//   [488,1032): Pdt[ko][m] (bf16) = v[m][ko]-w[m][ko]  (ko>=270 -> 0)
//   [1032,1052): out = 0  (out_gemm accumulates with atomics)
// ---------------------------------------------------------------------------
__global__ __launch_bounds__(256)
void prep_kernel(const float* __restrict__ G,
                 const float* __restrict__ v, const float* __restrict__ w,
                 __hip_bfloat16* __restrict__ Gt,
                 __hip_bfloat16* __restrict__ Pdt,
                 float* __restrict__ out) {
    const int b = blockIdx.x;
    if (b < 488) {
        __shared__ float tile[64][65];
        const int nTile = b % 61;
        const int mTile = b / 61;          // 0..7
        const int n0 = nTile * 64;
        const int m0 = mTile * 64;
        const int tc = threadIdx.x & 63;
        const int tr = threadIdx.x >> 6;
#pragma unroll
        for (int rr = 0; rr < 64; rr += 4) {
            int n = n0 + tc;
            tile[rr + tr][tc] = (n < LDIM) ? G[(size_t)(m0 + rr + tr) * LDIM + n] : 0.f;
        }
        __syncthreads();
        const int nr = threadIdx.x >> 2;          // n-row within tile
        const int ms = (threadIdx.x & 3) * 16;    // m-segment
        __hip_bfloat16 buf[16];
#pragma unroll
        for (int i = 0; i < 16; ++i)
            buf[i] = __float2bfloat16(tile[ms + i][nr]);
        __hip_bfloat16* dst = Gt + (size_t)(n0 + nr) * MDIM + m0 + ms;
        *reinterpret_cast<uint4*>(dst)     = *reinterpret_cast<uint4*>(&buf[0]);
        *reinterpret_cast<uint4*>(dst + 8) = *reinterpret_cast<uint4*>(&buf[8]);
    } else if (b < 1032) {
        int idx = (b - 488) * 256 + threadIdx.x;   // m*KOP + ko, exact range
        int m  = idx / KOP;
        int ko = idx - m * KOP;
        float val = (ko < KO) ? (v[m * KO + ko] - w[m * KO + ko]) : 0.f;
        Pdt[(size_t)ko * MDIM + m] = __float2bfloat16(val);
    } else {
        int idx = (b - 1032) * 256 + threadIdx.x;  // 20*256 = 5120 exact
        out[idx] = 0.f;
    }
}

// ---------------------------------------------------------------------------
// K1: T[ko][n] = sum_m Pdt[ko][m]*Gt[n][m]  (mfma 16x16x32 bf16, fragment
// mapping verified rounds 8-12).
// 1037 blocks x 4 waves; wave wv = K-chunk (128 m) of the block's single
// (kt, tile) output tile. Cross-wave reduction in LDS (12 KB), wave 0
// writes ONE fp32 T -> kills round-12's 66MB-write/66MB-read partials.
// Geometry keeps round-12's occupancy win: 4 blocks/CU, 16 waves/CU.
// __launch_bounds__(256,4) prevents the round-11 VGPR-60 spill.
// Bijective XCD swizzle (m204, nwg=1037): consecutive logical blocks
// (sharing the Gt panel: tile = lb/17) land on one XCD.
// ---------------------------------------------------------------------------
__global__ __launch_bounds__(256, 4)
void tmfma_kernel(const __hip_bfloat16* __restrict__ Pdt,
                  const __hip_bfloat16* __restrict__ Gt,
                  float* __restrict__ T) {
    const int orig = blockIdx.x;          // 0..1036
    const int xcd  = orig & 7;
    const int base = orig >> 3;
    const int lb   = (xcd < 5 ? xcd * 130 : 650 + (xcd - 5) * 129) + base;
    const int kt   = lb % 17;             // ko-tile
    const int tile = lb / 17;             // n-tile 0..60

    const int wv   = threadIdx.x >> 6;    // K-chunk 0..3
    const int lane = threadIdx.x & 63;
    const int n0   = tile * 64;
    const int ko0  = kt * 16;
    const int row  = lane & 15;
    const int kg   = lane >> 4;           // 0..3

    const __hip_bfloat16* Ap = Pdt + (size_t)(ko0 + row) * MDIM + wv * 128 + kg * 8;
    const __hip_bfloat16* Bp = Gt  + (size_t)(n0 + row) * MDIM + wv * 128 + kg * 8;

    f32x4 acc[4];
#pragma unroll
    for (int j = 0; j < 4; ++j) acc[j] = (f32x4){0.f, 0.f, 0.f, 0.f};

#pragma unroll
    for (int ks = 0; ks < 4; ++ks) {
        bfrag a = *reinterpret_cast<const bfrag*>(Ap + ks * 32);
#pragma unroll
        for (int j = 0; j < 4; ++j) {
            bfrag bfr = *reinterpret_cast<const bfrag*>(
                Bp + (size_t)j * 16 * MDIM + ks * 32);
            acc[j] = __builtin_amdgcn_mfma_f32_16x16x32_bf16(a, bfr, acc[j], 0, 0, 0);
        }
    }

    // cross-wave K reduction through LDS; wave 0 writes the final T.
    __shared__ f32x4 redL[3][64][4];      // 12 KB
    if (wv > 0) {
#pragma unroll
        for (int j = 0; j < 4; ++j) redL[wv - 1][lane][j] = acc[j];
    }
    __syncthreads();
    if (wv == 0) {
#pragma unroll
        for (int j = 0; j < 4; ++j) {
            acc[j] += redL[0][lane][j];
            acc[j] += redL[1][lane][j];
            acc[j] += redL[2][lane][j];
        }
#pragma unroll
        for (int j = 0; j < 4; ++j) {
            int col = n0 + j * 16 + row;
            if (col < LDIM) {
#pragma unroll
                for (int r = 0; r < 4; ++r) {
                    int ro = ko0 + kg * 4 + r;
                    if (ro < KO)
                        T[(size_t)ro * LDIM + col] = acc[j][r];
                }
            }
        }
    }
}

// ---------------------------------------------------------------------------
// K2: fold T (ko, pix) -> S[o][c*4096 + h*64 + w]; each T element read once.
// ---------------------------------------------------------------------------
__global__ __launch_bounds__(256)
void fold_kernel(const float* __restrict__ T, float* __restrict__ S) {
    int idx = blockIdx.x * 256 + threadIdx.x;   // o*CHW + chw
    if (idx >= ODIM * CHW) return;
    int o   = idx / CHW;
    int chw = idx - o * CHW;
    int c = chw >> 12;
    int h = (chw >> 6) & 63;
    int w = chw & 63;

    float s = 0.f;
    for (int i = 0; i < 3; ++i) {
        int pi = h - i;
        if ((unsigned)pi >= HOg) continue;
        for (int j = 0; j < 3; ++j) {
            int pj = w - j;
            if ((unsigned)pj >= HOg) continue;
            int ko = (c * 9 + i * 3 + j) * ODIM + o;
            s += T[(size_t)ko * LDIM + pi * HOg + pj];
        }
    }
    S[idx] = s;
}

// ---------------------------------------------------------------------------
// K3: out[b][o] += sum_{chw in slice} x[b][chw] * S[o][chw]
// Grid 384 = 64 image-octets x 6 chw-slices; S float4 reused for 8 images.
// ---------------------------------------------------------------------------
__global__ __launch_bounds__(256)
void out_gemm_kernel(const float* __restrict__ X,
                     const float* __restrict__ S,
                     float* __restrict__ out) {
    const int bg = blockIdx.x / 6;     // image octet
    const int sl = blockIdx.x % 6;     // chw slice
    const int b0 = bg * 8;
    const int i0 = sl * 512;           // float4 index base of slice
    const int tid = threadIdx.x;
    const int NV = CHW / 4;            // 3072

    const float4* X4 = reinterpret_cast<const float4*>(X);
    const float4* S4 = reinterpret_cast<const float4*>(S);

    float acc[8][ODIM];
#pragma unroll
    for (int im = 0; im < 8; ++im)
#pragma unroll
        for (int o = 0; o < ODIM; ++o) acc[im][o] = 0.f;

#pragma unroll
    for (int ii = 0; ii < 2; ++ii) {
        int i = i0 + tid + ii * 256;
        float4 xv[8];
#pragma unroll
        for (int im = 0; im < 8; ++im)
            xv[im] = X4[(size_t)(b0 + im) * NV + i];
#pragma unroll
        for (int o = 0; o < ODIM; ++o) {
            float4 sv = S4[(size_t)o * NV + i];
#pragma unroll
            for (int im = 0; im < 8; ++im) {
                acc[im][o] += xv[im].x * sv.x + xv[im].y * sv.y
                            + xv[im].z * sv.z + xv[im].w * sv.w;
            }
        }
    }

#pragma unroll
    for (int im = 0; im < 8; ++im)
#pragma unroll
        for (int o = 0; o < ODIM; ++o) {
            float s = acc[im][o];
            for (int off = 32; off > 0; off >>= 1)
                s += __shfl_down(s, off, 64);
            acc[im][o] = s;
        }

    __shared__ float red[4][80];
    const int wave = tid >> 6;
    const int lane = tid & 63;
    if (lane == 0) {
#pragma unroll
        for (int im = 0; im < 8; ++im)
#pragma unroll
            for (int o = 0; o < ODIM; ++o)
                red[wave][im * ODIM + o] = acc[im][o];
    }
    __syncthreads();
    if (tid < 80) {
        float t = red[0][tid] + red[1][tid] + red[2][tid] + red[3][tid];
        int im = tid / ODIM;
        int o  = tid - im * ODIM;
        atomicAdd(&out[(size_t)(b0 + im) * ODIM + o], t);
    }
}

extern "C" void kernel_launch(void* const* d_in, const int* in_sizes, int n_in,
                              void* d_out, int out_size, void* d_ws, size_t ws_size,
                              hipStream_t stream) {
    const float* x = (const float*)d_in[0];   // (512, 3, 64, 64)
    const float* G = (const float*)d_in[1];   // (512, 3844)
    const float* v = (const float*)d_in[2];   // (512, 27, 10)
    const float* w = (const float*)d_in[3];   // (512, 27, 10)
    float* out = (float*)d_out;               // (512, 10)

    // ws layout:
    //   T   fp32 [270][3844] =  4,151,520 B
    //   Gt  bf16 [3904][512] =  3,997,696 B
    //   Pdt bf16 [272][512]  =    278,528 B
    //   S   fp32 [10][12288] =    491,520 B
    char* wsb = (char*)d_ws;
    float*          T   = (float*)wsb;
    __hip_bfloat16* Gt  = (__hip_bfloat16*)(wsb + 4151520);
    __hip_bfloat16* Pdt = (__hip_bfloat16*)(wsb + 4151520 + 3997696);
    float*          S   = (float*)(wsb + 4151520 + 3997696 + 278528);

    prep_kernel<<<1052, 256, 0, stream>>>(G, v, w, Gt, Pdt, out);

    tmfma_kernel<<<1037, 256, 0, stream>>>(Pdt, Gt, T);

    fold_kernel<<<(ODIM * CHW + 255) / 256, 256, 0, stream>>>(T, S);

    out_gemm_kernel<<<384, 256, 0, stream>>>(x, S, out);
}

// Round 14
// 45.382 us; speedup vs baseline: 8.7976x; 1.0202x over previous
//
#include <hip/hip_runtime.h>
#include <hip/hip_bf16.h>

// ConvexReLUCNN: B=512, C=3, H=W=64, KERNEL=3
//   K=27, L=62*62=3844, M=512, O=10
#define ODIM   10
#define HOg    62
#define LDIM   3844
#define CHW    12288
#define BATCH  512
#define KO     270
#define KOP2   288        // ko padded to 9*32
#define MDIM   512        // reduction dim (neurons)
#define NPAD   3968       // n padded to 62*64 (31 tiles of 128)
#define LROW   72         // padded LDS row stride in bf16 (144 B)

typedef __attribute__((ext_vector_type(8))) short bfrag;   // 8 bf16 (4 VGPR)
typedef __attribute__((ext_vector_type(4))) float f32x4;

// ---------------------------------------------------------------------------
// K0 prep, 1092 blocks:
//   [0,496):     Gt[n][m] (bf16) = G[m][n], 64x64 LDS-tiled transpose (n<3968)
//   [496,1072):  Pdt[ko][m] (bf16) = v[m][ko]-w[m][ko]  (ko>=270 -> 0), 288 rows
//   [1072,1092): out = 0  (out_gemm accumulates with atomics)
// ---------------------------------------------------------------------------
__global__ __launch_bounds__(256)
void prep_kernel(const float* __restrict__ G,
                 const float* __restrict__ v, const float* __restrict__ w,
                 __hip_bfloat16* __restrict__ Gt,
                 __hip_bfloat16* __restrict__ Pdt,
                 float* __restrict__ out) {
    const int b = blockIdx.x;
    if (b < 496) {
        __shared__ float tile[64][65];
        const int nTile = b % 62;
        const int mTile = b / 62;          // 0..7
        const int n0 = nTile * 64;
        const int m0 = mTile * 64;
        const int tc = threadIdx.x & 63;
        const int tr = threadIdx.x >> 6;
#pragma unroll
        for (int rr = 0; rr < 64; rr += 4) {
            int n = n0 + tc;
            tile[rr + tr][tc] = (n < LDIM) ? G[(size_t)(m0 + rr + tr) * LDIM + n] : 0.f;
        }
        __syncthreads();
        const int nr = threadIdx.x >> 2;          // n-row within tile
        const int ms = (threadIdx.x & 3) * 16;    // m-segment
        __hip_bfloat16 buf[16];
#pragma unroll
        for (int i = 0; i < 16; ++i)
            buf[i] = __float2bfloat16(tile[ms + i][nr]);
        __hip_bfloat16* dst = Gt + (size_t)(n0 + nr) * MDIM + m0 + ms;
        *reinterpret_cast<uint4*>(dst)     = *reinterpret_cast<uint4*>(&buf[0]);
        *reinterpret_cast<uint4*>(dst + 8) = *reinterpret_cast<uint4*>(&buf[8]);
    } else if (b < 1072) {
        int idx = (b - 496) * 256 + threadIdx.x;   // ko*512 + m, exact range
        int ko = idx >> 9;
        int m  = idx & 511;
        float val = (ko < KO) ? (v[m * KO + ko] - w[m * KO + ko]) : 0.f;
        Pdt[idx] = __float2bfloat16(val);          // coalesced write
    } else {
        int idx = (b - 1072) * 256 + threadIdx.x;  // 20*256 = 5120 exact
        out[idx] = 0.f;
    }
}

// ---------------------------------------------------------------------------
// K1: T[ko][n] = sum_m Pdt[ko][m]*Gt[n][m]  — m97-style LDS-staged MFMA GEMM.
// Grid 279 = 9 kt x 31 nt (bijective XCD swizzle, m204). Block 256 = 4 waves.
// Tile 32ko x 128n, K-loop 8 x 64, double-buffered LDS with PADDED rows
// (stride 144 B -> frag reads <=2-way bank aliased = free). Global reads are
// coalesced 16B/lane streams (reg-staged, ds_write_b128); all fragment
// gathers moved to LDS — removes the direct-from-global gather pattern that
// pinned every previous tmfma variant at 24-28 us.
// Fragment/output mapping identical to rounds 8-13 (verified).
// ---------------------------------------------------------------------------
__global__ __launch_bounds__(256, 2)
void tmfma_kernel(const __hip_bfloat16* __restrict__ Pdt,
                  const __hip_bfloat16* __restrict__ Gt,
                  float* __restrict__ T) {
    // bijective XCD swizzle, nwg = 279 = 7*35 + 1*34
    const int orig = blockIdx.x;
    const int xcd  = orig & 7;
    const int q8   = orig >> 3;
    const int lb   = (xcd < 7 ? xcd * 35 : 245) + (xcd < 7 ? q8 : q8);
    const int lbf  = (xcd < 7 ? xcd * 35 + q8 : 245 + q8);
    const int kt   = lbf % 9;
    const int nt   = lbf / 9;              // 0..30
    (void)lb;
    const int ko0  = kt * 32;
    const int n0   = nt * 128;

    const int tid  = threadIdx.x;
    const int wv   = tid >> 6;
    const int lane = tid & 63;
    const int r16  = lane & 15;
    const int kg   = lane >> 4;            // 0..3

    __shared__ __hip_bfloat16 ldsA[2][32 * LROW];    //  9,216 B
    __shared__ __hip_bfloat16 ldsB[2][128 * LROW];   // 36,864 B

    // staging geometry: granule = 16B (8 bf16); thread t owns A granule t and
    // B granules {i*256+t}. row = g>>3, slot = g&7.
    const int srow  = tid >> 3;            // 0..31
    const int slot  = tid & 7;
    const __hip_bfloat16* pA = Pdt + (size_t)(ko0 + srow) * MDIM + slot * 8;
    const __hip_bfloat16* pB0 = Gt + (size_t)(n0 +       srow) * MDIM + slot * 8;
    const __hip_bfloat16* pB1 = Gt + (size_t)(n0 +  32 + srow) * MDIM + slot * 8;
    const __hip_bfloat16* pB2 = Gt + (size_t)(n0 +  64 + srow) * MDIM + slot * 8;
    const __hip_bfloat16* pB3 = Gt + (size_t)(n0 +  96 + srow) * MDIM + slot * 8;
    const int aoff  = srow * LROW + slot * 8;            // LDS elem offset (A)
    const int boff0 = (      srow) * LROW + slot * 8;
    const int boff1 = ( 32 + srow) * LROW + slot * 8;
    const int boff2 = ( 64 + srow) * LROW + slot * 8;
    const int boff3 = ( 96 + srow) * LROW + slot * 8;

    f32x4 acc00 = {0.f,0.f,0.f,0.f}, acc01 = {0.f,0.f,0.f,0.f};
    f32x4 acc10 = {0.f,0.f,0.f,0.f}, acc11 = {0.f,0.f,0.f,0.f};

    uint4 rA, rB0, rB1, rB2, rB3;

#define LDREGS(t)                                                         \
    do { int k0 = (t) * 64;                                               \
        rA  = *reinterpret_cast<const uint4*>(pA  + k0);                  \
        rB0 = *reinterpret_cast<const uint4*>(pB0 + k0);                  \
        rB1 = *reinterpret_cast<const uint4*>(pB1 + k0);                  \
        rB2 = *reinterpret_cast<const uint4*>(pB2 + k0);                  \
        rB3 = *reinterpret_cast<const uint4*>(pB3 + k0);                  \
    } while (0)

#define WRLDS(bsel)                                                       \
    do {                                                                  \
        *reinterpret_cast<uint4*>(&ldsA[bsel][aoff])  = rA;               \
        *reinterpret_cast<uint4*>(&ldsB[bsel][boff0]) = rB0;              \
        *reinterpret_cast<uint4*>(&ldsB[bsel][boff1]) = rB1;              \
        *reinterpret_cast<uint4*>(&ldsB[bsel][boff2]) = rB2;              \
        *reinterpret_cast<uint4*>(&ldsB[bsel][boff3]) = rB3;              \
    } while (0)

#define COMPUTE(bsel)                                                     \
    do {                                                                  \
        _Pragma("unroll")                                                 \
        for (int ks = 0; ks < 2; ++ks) {                                  \
            int kb = ks * 32 + kg * 8;                                    \
            bfrag a0 = *reinterpret_cast<const bfrag*>(                   \
                &ldsA[bsel][(r16) * LROW + kb]);                          \
            bfrag a1 = *reinterpret_cast<const bfrag*>(                   \
                &ldsA[bsel][(16 + r16) * LROW + kb]);                     \
            bfrag b0 = *reinterpret_cast<const bfrag*>(                   \
                &ldsB[bsel][(wv * 32 + r16) * LROW + kb]);                \
            bfrag b1 = *reinterpret_cast<const bfrag*>(                   \
                &ldsB[bsel][(wv * 32 + 16 + r16) * LROW + kb]);           \
            acc00 = __builtin_amdgcn_mfma_f32_16x16x32_bf16(a0, b0, acc00, 0, 0, 0); \
            acc01 = __builtin_amdgcn_mfma_f32_16x16x32_bf16(a0, b1, acc01, 0, 0, 0); \
            acc10 = __builtin_amdgcn_mfma_f32_16x16x32_bf16(a1, b0, acc10, 0, 0, 0); \
            acc11 = __builtin_amdgcn_mfma_f32_16x16x32_bf16(a1, b1, acc11, 0, 0, 0); \
        }                                                                 \
    } while (0)

    LDREGS(0);
    WRLDS(0);
    __syncthreads();

#pragma unroll
    for (int t = 0; t < 8; ++t) {
        const int cur = t & 1;
        if (t < 7) LDREGS(t + 1);       // next-step global loads in flight
        COMPUTE(cur);                    // ds_read + MFMA on current buffer
        if (t < 7) WRLDS(cur ^ 1);       // write next buffer (read at t-1, barrier-protected)
        __syncthreads();
    }
#undef LDREGS
#undef WRLDS
#undef COMPUTE

    // epilogue: C/D col = lane&15 (n), row = kg*4+reg (ko)  [verified r8-r13]
    const f32x4* accs[4] = { &acc00, &acc01, &acc10, &acc11 };
#pragma unroll
    for (int f = 0; f < 2; ++f) {
#pragma unroll
        for (int g = 0; g < 2; ++g) {
            const f32x4 a = *accs[f * 2 + g];
            int col = n0 + wv * 32 + g * 16 + r16;
            if (col < LDIM) {
#pragma unroll
                for (int r = 0; r < 4; ++r) {
                    int ro = ko0 + f * 16 + kg * 4 + r;
                    if (ro < KO)
                        T[(size_t)ro * LDIM + col] = a[r];
                }
            }
        }
    }
}

// ---------------------------------------------------------------------------
// K2: fold T (ko, pix) -> S[o][c*4096 + h*64 + w]; each T element read once.
// ---------------------------------------------------------------------------
__global__ __launch_bounds__(256)
void fold_kernel(const float* __restrict__ T, float* __restrict__ S) {
    int idx = blockIdx.x * 256 + threadIdx.x;   // o*CHW + chw
    if (idx >= ODIM * CHW) return;
    int o   = idx / CHW;
    int chw = idx - o * CHW;
    int c = chw >> 12;
    int h = (chw >> 6) & 63;
    int w = chw & 63;

    float s = 0.f;
    for (int i = 0; i < 3; ++i) {
        int pi = h - i;
        if ((unsigned)pi >= HOg) continue;
        for (int j = 0; j < 3; ++j) {
            int pj = w - j;
            if ((unsigned)pj >= HOg) continue;
            int ko = (c * 9 + i * 3 + j) * ODIM + o;
            s += T[(size_t)ko * LDIM + pi * HOg + pj];
        }
    }
    S[idx] = s;
}

// ---------------------------------------------------------------------------
// K3: out[b][o] += sum_{chw in slice} x[b][chw] * S[o][chw]
// Grid 768 = 64 image-octets x 12 chw-slices (256 float4 each) -> 12 waves/CU
// for the HBM-bound x read. S float4 reused for 8 images in registers.
// ---------------------------------------------------------------------------
__global__ __launch_bounds__(256)
void out_gemm_kernel(const float* __restrict__ X,
                     const float* __restrict__ S,
                     float* __restrict__ out) {
    const int bg = blockIdx.x / 12;    // image octet
    const int sl = blockIdx.x % 12;    // chw slice
    const int b0 = bg * 8;
    const int tid = threadIdx.x;
    const int NV = CHW / 4;            // 3072
    const int i  = sl * 256 + tid;     // float4 index

    const float4* X4 = reinterpret_cast<const float4*>(X);
    const float4* S4 = reinterpret_cast<const float4*>(S);

    float acc[8][ODIM];
#pragma unroll
    for (int im = 0; im < 8; ++im)
#pragma unroll
        for (int o = 0; o < ODIM; ++o) acc[im][o] = 0.f;

    float4 xv[8];
#pragma unroll
    for (int im = 0; im < 8; ++im)
        xv[im] = X4[(size_t)(b0 + im) * NV + i];
#pragma unroll
    for (int o = 0; o < ODIM; ++o) {
        float4 sv = S4[(size_t)o * NV + i];
#pragma unroll
        for (int im = 0; im < 8; ++im) {
            acc[im][o] += xv[im].x * sv.x + xv[im].y * sv.y
                        + xv[im].z * sv.z + xv[im].w * sv.w;
        }
    }

#pragma unroll
    for (int im = 0; im < 8; ++im)
#pragma unroll
        for (int o = 0; o < ODIM; ++o) {
            float s = acc[im][o];
            for (int off = 32; off > 0; off >>= 1)
                s += __shfl_down(s, off, 64);
            acc[im][o] = s;
        }

    __shared__ float red[4][80];
    const int wave = tid >> 6;
    const int lane = tid & 63;
    if (lane == 0) {
#pragma unroll
        for (int im = 0; im < 8; ++im)
#pragma unroll
            for (int o = 0; o < ODIM; ++o)
                red[wave][im * ODIM + o] = acc[im][o];
    }
    __syncthreads();
    if (tid < 80) {
        float t = red[0][tid] + red[1][tid] + red[2][tid] + red[3][tid];
        int im = tid / ODIM;
        int o  = tid - im * ODIM;
        atomicAdd(&out[(size_t)(b0 + im) * ODIM + o], t);
    }
}

extern "C" void kernel_launch(void* const* d_in, const int* in_sizes, int n_in,
                              void* d_out, int out_size, void* d_ws, size_t ws_size,
                              hipStream_t stream) {
    const float* x = (const float*)d_in[0];   // (512, 3, 64, 64)
    const float* G = (const float*)d_in[1];   // (512, 3844)
    const float* v = (const float*)d_in[2];   // (512, 27, 10)
    const float* w = (const float*)d_in[3];   // (512, 27, 10)
    float* out = (float*)d_out;               // (512, 10)

    // ws layout (16B-aligned):
    //   T   fp32 [270][3844] = 4,151,520 B
    //   Gt  bf16 [3968][512] = 4,063,232 B
    //   Pdt bf16 [288][512]  =   294,912 B
    //   S   fp32 [10][12288] =   491,520 B
    char* wsb = (char*)d_ws;
    float*          T   = (float*)wsb;
    __hip_bfloat16* Gt  = (__hip_bfloat16*)(wsb + 4151520);
    __hip_bfloat16* Pdt = (__hip_bfloat16*)(wsb + 4151520 + 4063232);
    float*          S   = (float*)(wsb + 4151520 + 4063232 + 294912);

    prep_kernel<<<1092, 256, 0, stream>>>(G, v, w, Gt, Pdt, out);

    tmfma_kernel<<<279, 256, 0, stream>>>(Pdt, Gt, T);

    fold_kernel<<<(ODIM * CHW + 255) / 256, 256, 0, stream>>>(T, S);

    out_gemm_kernel<<<768, 256, 0, stream>>>(x, S, out);
}